// Round 6
// baseline (1354.474 us; speedup 1.0000x reference)
//
#include <hip/hip_runtime.h>
#include <hip/hip_bf16.h>

#define E_NUM 64
#define IN_SZ 512
#define OUT_SZ 512
#define N_TOK 131072
#define CAP 3072

#define BM 256
#define BN 512
#define BK 32
#define THREADS 1024
#define RT_MAX 12   // CAP/BM
#define JT 16       // IN_SZ/BK
#define NWG (E_NUM * RT_MAX)

typedef __attribute__((ext_vector_type(8))) short short8;
typedef __attribute__((ext_vector_type(4))) float f32x4;

__device__ inline unsigned short f2bf(float f) {
    unsigned int u = __float_as_uint(f);
    unsigned int r = (u + 0x7FFF + ((u >> 16) & 1)) >> 16;
    return (unsigned short)r;
}

#define GLOAD_LDS16(g, l)                                                     \
    __builtin_amdgcn_global_load_lds(                                         \
        (const __attribute__((address_space(1))) void*)(g),                   \
        (__attribute__((address_space(3))) void*)(l), 16, 0, 0)

// ---------------- kernel 1: exclusive prefix sum of expert sizes ----------
__global__ void offsets_kernel(const int* __restrict__ sizes, int* __restrict__ offs) {
    int e = threadIdx.x;
    int s = 0;
    for (int i = 0; i < e; ++i) s += sizes[i];
    offs[e] = s;
}

// ---------------- kernel 2: W [E][K][N] f32 -> WT [E][N][K] bf16 ----------
__global__ __launch_bounds__(256) void prep_wt(const float* __restrict__ W,
                                               unsigned short* __restrict__ WT) {
    __shared__ float t[32][33];
    int k0 = blockIdx.x * 32, n0 = blockIdx.y * 32, e = blockIdx.z;
    const float* We = W + (size_t)e * IN_SZ * OUT_SZ;
    int tid = threadIdx.x;
    int r = tid >> 3, c4 = (tid & 7) * 4;
    float4 v = *(const float4*)(We + (size_t)(k0 + r) * OUT_SZ + n0 + c4);
    t[r][c4 + 0] = v.x; t[r][c4 + 1] = v.y; t[r][c4 + 2] = v.z; t[r][c4 + 3] = v.w;
    __syncthreads();
    ushort4 o;
    o.x = f2bf(t[c4 + 0][r]);
    o.y = f2bf(t[c4 + 1][r]);
    o.z = f2bf(t[c4 + 2][r]);
    o.w = f2bf(t[c4 + 3][r]);
    unsigned short* O = WT + (size_t)e * IN_SZ * OUT_SZ + (size_t)(n0 + r) * IN_SZ + k0 + c4;
    *(ushort4*)O = o;
}

// ---------------- kernel 3: grouped GEMM, 256x512 tile --------------------
// Traffic-minimal tile: A read exactly once (BN=512 -> one col-tile),
// B re-read factor = ceil(size_e/256) ~ 8-10, L2-resident via XCD chunking.
// Swizzle (0-conflict, R2/R4/R5): 16B-slot ^= (row>>1)&3 within 64B k-row.
// 3-buffer counted-vmcnt pipeline; per-thread VMEM/iter = 2 A-loads +
// 2 gload_lds -> vmcnt(4) at the barrier keeps the newest iter in flight.
__global__ __launch_bounds__(THREADS, 1) void gemm_moe(
    const float* __restrict__ A, const int* __restrict__ sizes,
    const unsigned short* __restrict__ WT, const int* __restrict__ offs,
    float* __restrict__ out)
{
    // bijective XCD swizzle: 768 blocks, 96 per XCD chunk (8 experts/XCD)
    int b0 = blockIdx.x;
    int wg = (b0 & 7) * (NWG / 8) + (b0 >> 3);
    int rt = wg % RT_MAX;
    int e  = wg / RT_MAX;

    int size_e = sizes[e];
    int rows0 = rt * BM;
    if (rows0 >= size_e) return;
    int off_e = offs[e];
    int rows_rem = size_e - rows0;                      // >= 1
    int maxr = (rows_rem < BM ? rows_rem : BM) - 1;

    __shared__ unsigned short lsA[3][BM * BK];   // 3 x 16 KB
    __shared__ unsigned short lsB[3][BN * BK];   // 3 x 32 KB

    int tid = threadIdx.x, l = tid & 63, w = tid >> 6;   // w in 0..15
    const char* WTe = (const char*)(WT + (size_t)e * IN_SZ * OUT_SZ);
    const float* Abase = A + (size_t)(off_e + rows0) * IN_SZ;

    // ---- A staging geometry (i<2: idx = tid + 1024*i) ----
    const float* ap[2];
    int aw[2];
    #pragma unroll
    for (int i = 0; i < 2; ++i) {
        int idx = tid + THREADS * i;        // 0..2047 float4 units
        int row = idx >> 3, c4 = idx & 7;   // row 0..255
        int gr = row <= maxr ? row : maxr;
        ap[i] = Abase + (size_t)gr * IN_SZ + c4 * 4;
        aw[i] = row * 64 + ((c4 * 8) ^ (((row >> 1) & 3) << 4));
    }
    // ---- B staging geometry (chunks c = w*2+i, c<32; LDS row c*16+l>>2) --
    const char* gB[2];
    #pragma unroll
    for (int i = 0; i < 2; ++i) {
        int c = w * 2 + i;
        int n = c * 16 + (l >> 2);
        int csrc = ((l & 3) * 16) ^ (((l >> 3) & 3) << 4);
        gB[i] = WTe + (size_t)n * (IN_SZ * 2) + csrc;
    }

    float4 ar[2][2];   // 2 in-flight A register sets

    auto loadA = [&](int kt, int p) {
        #pragma unroll
        for (int i = 0; i < 2; ++i)
            ar[p][i] = *(const float4*)(ap[i] + kt * BK);
    };
    auto writeA = [&](int buf, int p) {
        #pragma unroll
        for (int i = 0; i < 2; ++i) {
            ushort4 pk;
            pk.x = f2bf(ar[p][i].x); pk.y = f2bf(ar[p][i].y);
            pk.z = f2bf(ar[p][i].z); pk.w = f2bf(ar[p][i].w);
            *(ushort4*)((char*)&lsA[buf][0] + aw[i]) = pk;
        }
    };
    auto stageB = [&](int buf, int kt) {
        #pragma unroll
        for (int i = 0; i < 2; ++i)
            GLOAD_LDS16(gB[i] + kt * 64, &lsB[buf][(w * 2 + i) * 512]);
    };

    int wm = (w >> 2) * 64, wn = (w & 3) * 128;
    int lrow = l & 15;
    int cb = ((l >> 4) * 16) ^ (((l >> 1) & 3) << 4);

    f32x4 acc[4][8] = {};

    #define FRAGS_AND_MFMA(buf)                                               \
        {                                                                     \
            const char* pA = (const char*)&lsA[buf][0];                       \
            const char* pB = (const char*)&lsB[buf][0];                       \
            short8 af[4];                                                     \
            _Pragma("unroll")                                                 \
            for (int m = 0; m < 4; ++m)                                       \
                af[m] = *(const short8*)(pA + (wm + m * 16 + lrow) * 64 + cb);\
            short8 bfr[8];                                                    \
            _Pragma("unroll")                                                 \
            for (int n = 0; n < 8; ++n)                                       \
                bfr[n] = *(const short8*)(pB + (wn + n * 16 + lrow) * 64 + cb);\
            asm volatile("s_waitcnt lgkmcnt(0)" ::: "memory");                \
            __builtin_amdgcn_sched_barrier(0);                                \
            __builtin_amdgcn_s_setprio(1);                                    \
            _Pragma("unroll")                                                 \
            for (int m = 0; m < 4; ++m)                                       \
                _Pragma("unroll")                                             \
                for (int n = 0; n < 8; ++n)                                   \
                    acc[m][n] = __builtin_amdgcn_mfma_f32_16x16x32_bf16(      \
                        af[m], bfr[n], acc[m][n], 0, 0, 0);                   \
            __builtin_amdgcn_s_setprio(0);                                    \
        }

    // ---- prologue: tiles 0,1 staged; A0 written ----
    loadA(0, 0); stageB(0, 0);
    loadA(1, 1); stageB(1, 1);
    writeA(0, 0);                                   // implicit wait on A0 loads
    asm volatile("s_waitcnt vmcnt(4)" ::: "memory");   // B0 landed; A1,B1 fly
    __builtin_amdgcn_sched_barrier(0);
    asm volatile("s_waitcnt lgkmcnt(0)" ::: "memory"); // A0 ds_writes visible
    __builtin_amdgcn_sched_barrier(0);
    __builtin_amdgcn_s_barrier();
    __builtin_amdgcn_sched_barrier(0);

    // ---- main loop, fully unrolled (all buf/set indices static) ----
    #pragma unroll
    for (int j = 0; j < JT; ++j) {
        if (j + 2 < JT) {
            loadA(j + 2, (j + 2) & 1);
            stageB((j + 2) % 3, j + 2);
        }
        FRAGS_AND_MFMA(j % 3);
        if (j + 1 < JT)
            writeA((j + 1) % 3, (j + 1) & 1);
        if (j < JT - 1) {
            if (j < JT - 2) {
                asm volatile("s_waitcnt vmcnt(4)" ::: "memory");
            } else {
                asm volatile("s_waitcnt vmcnt(0)" ::: "memory");
            }
            __builtin_amdgcn_sched_barrier(0);
            asm volatile("s_waitcnt lgkmcnt(0)" ::: "memory");
            __builtin_amdgcn_sched_barrier(0);
            __builtin_amdgcn_s_barrier();
            __builtin_amdgcn_sched_barrier(0);
        }
    }

    // epilogue: C/D layout col = lane&15, row = (lane>>4)*4 + reg
    float* outb = out + (size_t)(off_e + rows0) * OUT_SZ + wn;
    #pragma unroll
    for (int m = 0; m < 4; ++m) {
        #pragma unroll
        for (int j = 0; j < 4; ++j) {
            int rl = wm + m * 16 + (l >> 4) * 4 + j;
            if (rl < rows_rem) {
                float* po = outb + (size_t)rl * OUT_SZ + lrow;
                #pragma unroll
                for (int n = 0; n < 8; ++n)
                    po[n * 16] = acc[m][n][j];
            }
        }
    }
}

extern "C" void kernel_launch(void* const* d_in, const int* in_sizes, int n_in,
                              void* d_out, int out_size, void* d_ws, size_t ws_size,
                              hipStream_t stream) {
    const float* A      = (const float*)d_in[0];
    const int* sizes    = (const int*)d_in[1];
    const float* W      = (const float*)d_in[2];
    float* out          = (float*)d_out;

    unsigned short* WT  = (unsigned short*)d_ws;                       // 32 MB
    int* offs           = (int*)((char*)d_ws + (size_t)E_NUM * IN_SZ * OUT_SZ * 2);

    offsets_kernel<<<1, E_NUM, 0, stream>>>(sizes, offs);
    prep_wt<<<dim3(IN_SZ / 32, OUT_SZ / 32, E_NUM), 256, 0, stream>>>(W, WT);
    gemm_moe<<<NWG, THREADS, 0, stream>>>(A, sizes, WT, offs, out);
}

// Round 7
// 425.316 us; speedup vs baseline: 3.1846x; 3.1846x over previous
//
#include <hip/hip_runtime.h>
#include <hip/hip_bf16.h>

#define E_NUM 64
#define IN_SZ 512
#define OUT_SZ 512
#define N_TOK 131072
#define CAP 3072

#define BM 128
#define BN 256
#define BK 32
#define THREADS 256
#define RT_MAX 24   // CAP/BM
#define CT_NUM 2    // OUT/BN
#define JT 16       // IN_SZ/BK

typedef __attribute__((ext_vector_type(8))) short short8;
typedef __attribute__((ext_vector_type(4))) float f32x4;

__device__ inline unsigned short f2bf(float f) {
    unsigned int u = __float_as_uint(f);
    unsigned int r = (u + 0x7FFF + ((u >> 16) & 1)) >> 16;
    return (unsigned short)r;
}

#define GLOAD_LDS16(g, l)                                                     \
    __builtin_amdgcn_global_load_lds(                                         \
        (const __attribute__((address_space(1))) void*)(g),                   \
        (__attribute__((address_space(3))) void*)(l), 16, 0, 0)

// ---------------- kernel 1: exclusive prefix sum of expert sizes ----------
__global__ void offsets_kernel(const int* __restrict__ sizes, int* __restrict__ offs) {
    int e = threadIdx.x;
    int s = 0;
    for (int i = 0; i < e; ++i) s += sizes[i];
    offs[e] = s;
}

// ---------------- kernel 2: W [E][K][N] f32 -> WT [E][N][K] bf16 ----------
__global__ __launch_bounds__(256) void prep_wt(const float* __restrict__ W,
                                               unsigned short* __restrict__ WT) {
    __shared__ float t[32][33];
    int k0 = blockIdx.x * 32, n0 = blockIdx.y * 32, e = blockIdx.z;
    const float* We = W + (size_t)e * IN_SZ * OUT_SZ;
    int tid = threadIdx.x;
    int r = tid >> 3, c4 = (tid & 7) * 4;
    float4 v = *(const float4*)(We + (size_t)(k0 + r) * OUT_SZ + n0 + c4);
    t[r][c4 + 0] = v.x; t[r][c4 + 1] = v.y; t[r][c4 + 2] = v.z; t[r][c4 + 3] = v.w;
    __syncthreads();
    ushort4 o;
    o.x = f2bf(t[c4 + 0][r]);
    o.y = f2bf(t[c4 + 1][r]);
    o.z = f2bf(t[c4 + 2][r]);
    o.w = f2bf(t[c4 + 3][r]);
    unsigned short* O = WT + (size_t)e * IN_SZ * OUT_SZ + (size_t)(n0 + r) * IN_SZ + k0 + c4;
    *(ushort4*)O = o;
}

// ---------------- kernel 3: grouped GEMM, deep A-prefetch -----------------
// R4 config (best: 176us) + ONE change: pipeline depth.
//   A: 4 reg sets, loadA(j+4) -> writeA(j+1) => ~3 iters (~1200+ cy) of slack
//      vs ~900 cy HBM latency (was ~1.3 iters => per-iter stall, the R1-R5 wall).
//   B: 4 LDS buffers, stageB(j+3) consumed at j+3 => 3-iter slack.
// Swizzle (verified 0-conflict): 16B-slot ^= (row>>1)&3 within 64B k-row;
// B pre-swizzled at global source (involution, rule #21).
// Exact vmcnt table at each barrier; never drains in-flight prefetch.
__global__ __launch_bounds__(THREADS, 2) void gemm_moe(
    const float* __restrict__ A, const int* __restrict__ sizes,
    const unsigned short* __restrict__ WT, const int* __restrict__ offs,
    float* __restrict__ out)
{
    // bijective XCD swizzle: 3072 blocks, 384 per XCD chunk
    int b0 = blockIdx.x;
    int wg = (b0 & 7) * (E_NUM * RT_MAX * CT_NUM / 8) + (b0 >> 3);
    int ct = wg & (CT_NUM - 1);
    int rt = (wg >> 1) % RT_MAX;
    int e  = wg / (RT_MAX * CT_NUM);

    int size_e = sizes[e];
    int rows0 = rt * BM;
    if (rows0 >= size_e) return;
    int off_e = offs[e];
    int rows_rem = size_e - rows0;                      // >= 1
    int maxr = (rows_rem < BM ? rows_rem : BM) - 1;

    __shared__ unsigned short lsA[2][BM * BK];   // 2 x 8 KB
    __shared__ unsigned short lsB[4][BN * BK];   // 4 x 16 KB  -> 80 KB total

    int tid = threadIdx.x, l = tid & 63, w = tid >> 6;
    const char* WTe = (const char*)(WT + (size_t)e * IN_SZ * OUT_SZ);
    const float* Abase = A + (size_t)(off_e + rows0) * IN_SZ;

    // ---- A staging geometry (per i: idx = tid + 256*i) ----
    const float* ap[4];
    int aw[4];
    #pragma unroll
    for (int i = 0; i < 4; ++i) {
        int idx = tid + THREADS * i;
        int row = idx >> 3, c4 = idx & 7;
        int gr = row <= maxr ? row : maxr;
        ap[i] = Abase + (size_t)gr * IN_SZ + c4 * 4;
        aw[i] = row * 64 + ((c4 * 8) ^ (((row >> 1) & 3) << 4));
    }
    // ---- B staging geometry (chunks c = w*4+i; LDS row = c*16 + l>>2) ----
    const char* gB[4];
    #pragma unroll
    for (int i = 0; i < 4; ++i) {
        int c = w * 4 + i;
        int n = c * 16 + (l >> 2);
        int csrc = ((l & 3) * 16) ^ (((l >> 3) & 3) << 4);
        gB[i] = WTe + (size_t)(ct * BN + n) * (IN_SZ * 2) + csrc;
    }

    float4 ar[4][4];   // FOUR in-flight A register sets (deep prefetch)

    auto loadA = [&](int kt, int p) {
        #pragma unroll
        for (int i = 0; i < 4; ++i)
            ar[p][i] = *(const float4*)(ap[i] + kt * BK);
    };
    auto writeA = [&](int buf, int p) {
        #pragma unroll
        for (int i = 0; i < 4; ++i) {
            ushort4 pk;
            pk.x = f2bf(ar[p][i].x); pk.y = f2bf(ar[p][i].y);
            pk.z = f2bf(ar[p][i].z); pk.w = f2bf(ar[p][i].w);
            *(ushort4*)((char*)&lsA[buf][0] + aw[i]) = pk;
        }
    };
    auto stageB = [&](int buf, int kt) {
        #pragma unroll
        for (int i = 0; i < 4; ++i)
            GLOAD_LDS16(gB[i] + kt * 64, &lsB[buf][(w * 4 + i) * 512]);
    };

    int wm = (w >> 1) * 64, wn = (w & 1) * 128;
    int lrow = l & 15;
    int cb = ((l >> 4) * 16) ^ (((l >> 1) & 3) << 4);

    f32x4 acc[4][8] = {};

    #define FRAGS_AND_MFMA(bufA, bufB)                                        \
        {                                                                     \
            const char* pA = (const char*)&lsA[bufA][0];                      \
            const char* pB = (const char*)&lsB[bufB][0];                      \
            short8 af[4];                                                     \
            _Pragma("unroll")                                                 \
            for (int m = 0; m < 4; ++m)                                       \
                af[m] = *(const short8*)(pA + (wm + m * 16 + lrow) * 64 + cb);\
            short8 bfr[8];                                                    \
            _Pragma("unroll")                                                 \
            for (int n = 0; n < 8; ++n)                                       \
                bfr[n] = *(const short8*)(pB + (wn + n * 16 + lrow) * 64 + cb);\
            asm volatile("s_waitcnt lgkmcnt(0)" ::: "memory");                \
            __builtin_amdgcn_sched_barrier(0);                                \
            __builtin_amdgcn_s_setprio(1);                                    \
            _Pragma("unroll")                                                 \
            for (int m = 0; m < 4; ++m)                                       \
                _Pragma("unroll")                                             \
                for (int n = 0; n < 8; ++n)                                   \
                    acc[m][n] = __builtin_amdgcn_mfma_f32_16x16x32_bf16(      \
                        af[m], bfr[n], acc[m][n], 0, 0, 0);                   \
            __builtin_amdgcn_s_setprio(0);                                    \
        }

    // ---- prologue: A tiles 0-3 -> regs, B tiles 0-2 -> LDS, A0 -> LDS ----
    loadA(0, 0); stageB(0, 0);
    loadA(1, 1); stageB(1, 1);
    loadA(2, 2); stageB(2, 2);
    loadA(3, 3);
    writeA(0, 0);                       // implicit exact vmcnt wait on A0 only
    // outstanding after: A1,B1,A2,B2,A3 = 20 ops; B0 complete.
    asm volatile("s_waitcnt vmcnt(20)" ::: "memory");
    __builtin_amdgcn_sched_barrier(0);
    asm volatile("s_waitcnt lgkmcnt(0)" ::: "memory");
    __builtin_amdgcn_sched_barrier(0);
    __builtin_amdgcn_s_barrier();
    __builtin_amdgcn_sched_barrier(0);

    // ---- main loop, fully unrolled; per-iter VMEM = 4 A + 4 B ops --------
    #pragma unroll
    for (int j = 0; j < JT; ++j) {
        if (j + 4 < JT) loadA(j + 4, (j + 4) & 3);
        if (j + 3 < JT) stageB((j + 3) & 3, j + 3);
        FRAGS_AND_MFMA(j & 1, j & 3);
        if (j + 1 < JT) writeA((j + 1) & 1, (j + 1) & 3);
        if (j < JT - 1) {
            // wait: B(j+1) landed; keep newer prefetch in flight
            if (j <= 1)       { asm volatile("s_waitcnt vmcnt(20)" ::: "memory"); }
            else if (j <= 11) { asm volatile("s_waitcnt vmcnt(16)" ::: "memory"); }
            else if (j == 12) { asm volatile("s_waitcnt vmcnt(12)" ::: "memory"); }
            else if (j == 13) { asm volatile("s_waitcnt vmcnt(4)"  ::: "memory"); }
            else              { asm volatile("s_waitcnt vmcnt(0)"  ::: "memory"); }
            __builtin_amdgcn_sched_barrier(0);
            asm volatile("s_waitcnt lgkmcnt(0)" ::: "memory");
            __builtin_amdgcn_sched_barrier(0);
            __builtin_amdgcn_s_barrier();
            __builtin_amdgcn_sched_barrier(0);
        }
    }

    // epilogue: C/D layout col = lane&15, row = (lane>>4)*4 + reg
    float* outb = out + (size_t)(off_e + rows0) * OUT_SZ + ct * BN + wn;
    #pragma unroll
    for (int m = 0; m < 4; ++m) {
        #pragma unroll
        for (int j = 0; j < 4; ++j) {
            int rl = wm + m * 16 + (l >> 4) * 4 + j;
            if (rl < rows_rem) {
                float* po = outb + (size_t)rl * OUT_SZ + lrow;
                #pragma unroll
                for (int n = 0; n < 8; ++n)
                    po[n * 16] = acc[m][n][j];
            }
        }
    }
}

extern "C" void kernel_launch(void* const* d_in, const int* in_sizes, int n_in,
                              void* d_out, int out_size, void* d_ws, size_t ws_size,
                              hipStream_t stream) {
    const float* A      = (const float*)d_in[0];
    const int* sizes    = (const int*)d_in[1];
    const float* W      = (const float*)d_in[2];
    float* out          = (float*)d_out;

    unsigned short* WT  = (unsigned short*)d_ws;                       // 32 MB
    int* offs           = (int*)((char*)d_ws + (size_t)E_NUM * IN_SZ * OUT_SZ * 2);

    offsets_kernel<<<1, E_NUM, 0, stream>>>(sizes, offs);
    prep_wt<<<dim3(IN_SZ / 32, OUT_SZ / 32, E_NUM), 256, 0, stream>>>(W, WT);
    gemm_moe<<<E_NUM * RT_MAX * CT_NUM, THREADS, 0, stream>>>(A, sizes, WT, offs, out);
}

// Round 8
// 370.384 us; speedup vs baseline: 3.6569x; 1.1483x over previous
//
#include <hip/hip_runtime.h>
#include <hip/hip_bf16.h>

#define E_NUM 64
#define IN_SZ 512
#define OUT_SZ 512
#define N_TOK 131072
#define CAP 3072

#define BM 128
#define BN 256
#define THREADS 256
#define RT_MAX 24   // CAP/BM
#define CT_NUM 2    // OUT/BN
#define JT 16       // IN_SZ/32

typedef __attribute__((ext_vector_type(8))) short short8;
typedef __attribute__((ext_vector_type(4))) float f32x4;
typedef __attribute__((ext_vector_type(4))) unsigned int u32x4;

__device__ inline unsigned short f2bf(float f) {
    unsigned int u = __float_as_uint(f);
    unsigned int r = (u + 0x7FFF + ((u >> 16) & 1)) >> 16;
    return (unsigned short)r;
}

// packed fp32x2 -> bf16x2 (RNE), single HW instr on gfx950
__device__ inline unsigned int cvtpk(float a, float b) {
    unsigned int r;
    asm("v_cvt_pk_bf16_f32 %0, %1, %2" : "=v"(r) : "v"(a), "v"(b));
    return r;
}

// ---------------- kernel 1: exclusive prefix sum of expert sizes ----------
__global__ void offsets_kernel(const int* __restrict__ sizes, int* __restrict__ offs) {
    int e = threadIdx.x;
    int s = 0;
    for (int i = 0; i < e; ++i) s += sizes[i];
    offs[e] = s;
}

// ---------------- kernel 2: W [E][K][N] f32 -> WT [E][N][K] bf16 ----------
__global__ __launch_bounds__(256) void prep_wt(const float* __restrict__ W,
                                               unsigned short* __restrict__ WT) {
    __shared__ float t[32][33];
    int k0 = blockIdx.x * 32, n0 = blockIdx.y * 32, e = blockIdx.z;
    const float* We = W + (size_t)e * IN_SZ * OUT_SZ;
    int tid = threadIdx.x;
    int r = tid >> 3, c4 = (tid & 7) * 4;
    float4 v = *(const float4*)(We + (size_t)(k0 + r) * OUT_SZ + n0 + c4);
    t[r][c4 + 0] = v.x; t[r][c4 + 1] = v.y; t[r][c4 + 2] = v.z; t[r][c4 + 3] = v.w;
    __syncthreads();
    ushort4 o;
    o.x = f2bf(t[c4 + 0][r]);
    o.y = f2bf(t[c4 + 1][r]);
    o.z = f2bf(t[c4 + 2][r]);
    o.w = f2bf(t[c4 + 3][r]);
    unsigned short* O = WT + (size_t)e * IN_SZ * OUT_SZ + (size_t)(n0 + r) * IN_SZ + k0 + c4;
    *(ushort4*)O = o;
}

// ---------------- kernel 3: LDS-free direct-fragment GEMM -----------------
// Both MFMA operands load straight from global into fragment layout:
//   A (fp32 [M][512]):  lane l, frag m: row = wm+m*16+(l&15), 32B at k-off
//     (l>>4)*32 -> wave covers 16 rows x 128B fully-used lines. cvt_pk->bf16.
//   B (WT bf16 [N][512], k-contig): lane l, frag n: row = wn+n*16+(l&15),
//     16B at (l>>4)*16 -> 16 rows x 64B fully-used lines.
// No LDS, no barriers: waves free-run; compiler emits exact per-register
// vmcnt waits; latency hidden by TLP + depth-1 prefetch (B double-set,
// A single fp32 set recycled after cvt).
__global__ __launch_bounds__(THREADS, 2) void gemm_moe(
    const float* __restrict__ A, const int* __restrict__ sizes,
    const unsigned short* __restrict__ WT, const int* __restrict__ offs,
    float* __restrict__ out)
{
    // bijective XCD swizzle: 3072 blocks, 384 per XCD chunk
    int b0 = blockIdx.x;
    int wg = (b0 & 7) * (E_NUM * RT_MAX * CT_NUM / 8) + (b0 >> 3);
    int ct = wg & (CT_NUM - 1);
    int rt = (wg >> 1) % RT_MAX;
    int e  = wg / (RT_MAX * CT_NUM);

    int size_e = sizes[e];
    int rows0 = rt * BM;
    if (rows0 >= size_e) return;
    int off_e = offs[e];
    int rows_rem = size_e - rows0;                      // >= 1
    int maxr = (rows_rem < BM ? rows_rem : BM) - 1;

    int tid = threadIdx.x, l = tid & 63, w = tid >> 6;
    int wm = (w >> 1) * 64, wn = (w & 1) * 128;
    int lrow = l & 15, kq = l >> 4;                     // kq in 0..3

    const char* Abase = (const char*)(A + (size_t)(off_e + rows0) * IN_SZ);
    const char* Bbase = (const char*)WT + (size_t)e * IN_SZ * OUT_SZ * 2
                      + (size_t)(ct * BN + wn + lrow) * (IN_SZ * 2) + kq * 16;

    // per-m A byte offsets (row clamped to maxr) + per-lane k offset
    int aoff[4];
    #pragma unroll
    for (int m = 0; m < 4; ++m) {
        int r = wm + m * 16 + lrow;
        r = r <= maxr ? r : maxr;
        aoff[m] = r * (IN_SZ * 4) + kq * 32;
    }

    f32x4 ar[4][2];        // ONE fp32 A set (recycled each iter after cvt)
    short8 br[2][8];       // B double-set

    #define LOADA(kt)                                                         \
        _Pragma("unroll")                                                     \
        for (int m = 0; m < 4; ++m) {                                         \
            ar[m][0] = *(const f32x4*)(Abase + aoff[m] + (kt) * 128);         \
            ar[m][1] = *(const f32x4*)(Abase + aoff[m] + (kt) * 128 + 16);    \
        }
    #define LOADB(kt, s)                                                      \
        _Pragma("unroll")                                                     \
        for (int n = 0; n < 8; ++n)                                           \
            br[s][n] = *(const short8*)(Bbase + n * (16 * IN_SZ * 2) + (kt) * 64);

    f32x4 acc[4][8] = {};

    LOADA(0);
    LOADB(0, 0);

    #pragma unroll
    for (int kt = 0; kt < JT; ++kt) {
        // convert A(kt) fp32 -> bf16 fragments (waits only on A loads)
        u32x4 au[4];
        #pragma unroll
        for (int m = 0; m < 4; ++m) {
            au[m][0] = cvtpk(ar[m][0][0], ar[m][0][1]);
            au[m][1] = cvtpk(ar[m][0][2], ar[m][0][3]);
            au[m][2] = cvtpk(ar[m][1][0], ar[m][1][1]);
            au[m][3] = cvtpk(ar[m][1][2], ar[m][1][3]);
        }
        // recycle fp32 regs: issue next A; issue next B into other set
        if (kt + 1 < JT) {
            LOADA(kt + 1);
            LOADB(kt + 1, (kt + 1) & 1);
        }
        // MFMA on current fragments (compiler waits the right vmcnt for br)
        #pragma unroll
        for (int m = 0; m < 4; ++m) {
            short8 af = __builtin_bit_cast(short8, au[m]);
            #pragma unroll
            for (int n = 0; n < 8; ++n)
                acc[m][n] = __builtin_amdgcn_mfma_f32_16x16x32_bf16(
                    af, br[kt & 1][n], acc[m][n], 0, 0, 0);
        }
    }

    // epilogue: C/D layout col = lane&15, row = (lane>>4)*4 + reg
    float* outb = out + (size_t)(off_e + rows0) * OUT_SZ + ct * BN + wn;
    #pragma unroll
    for (int m = 0; m < 4; ++m) {
        #pragma unroll
        for (int j = 0; j < 4; ++j) {
            int rl = wm + m * 16 + kq * 4 + j;
            if (rl < rows_rem) {
                float* po = outb + (size_t)rl * OUT_SZ + lrow;
                #pragma unroll
                for (int n = 0; n < 8; ++n)
                    po[n * 16] = acc[m][n][j];
            }
        }
    }
}

extern "C" void kernel_launch(void* const* d_in, const int* in_sizes, int n_in,
                              void* d_out, int out_size, void* d_ws, size_t ws_size,
                              hipStream_t stream) {
    const float* A      = (const float*)d_in[0];
    const int* sizes    = (const int*)d_in[1];
    const float* W      = (const float*)d_in[2];
    float* out          = (float*)d_out;

    unsigned short* WT  = (unsigned short*)d_ws;                       // 32 MB
    int* offs           = (int*)((char*)d_ws + (size_t)E_NUM * IN_SZ * OUT_SZ * 2);

    offsets_kernel<<<1, E_NUM, 0, stream>>>(sizes, offs);
    prep_wt<<<dim3(IN_SZ / 32, OUT_SZ / 32, E_NUM), 256, 0, stream>>>(W, WT);
    gemm_moe<<<E_NUM * RT_MAX * CT_NUM, THREADS, 0, stream>>>(A, sizes, WT, offs, out);
}

// Round 9
// 187.146 us; speedup vs baseline: 7.2375x; 1.9791x over previous
//
#include <hip/hip_runtime.h>
#include <hip/hip_bf16.h>

#define E_NUM 64
#define IN_SZ 512
#define OUT_SZ 512
#define N_TOK 131072
#define CAP 3072

#define BM 128
#define BN 256
#define BK 32
#define THREADS 256
#define RT_MAX 24   // CAP/BM
#define CT_NUM 2    // OUT/BN
#define JT 16       // IN_SZ/BK

typedef __attribute__((ext_vector_type(8))) short short8;
typedef __attribute__((ext_vector_type(4))) float f32x4;
typedef __attribute__((ext_vector_type(4))) unsigned int u32x4;

__device__ inline unsigned short f2bf(float f) {
    unsigned int u = __float_as_uint(f);
    unsigned int r = (u + 0x7FFF + ((u >> 16) & 1)) >> 16;
    return (unsigned short)r;
}

// packed fp32x2 -> bf16x2 (RNE), single HW instr on gfx950
__device__ inline unsigned int cvtpk(float a, float b) {
    unsigned int r;
    asm("v_cvt_pk_bf16_f32 %0, %1, %2" : "=v"(r) : "v"(a), "v"(b));
    return r;
}

#define GLOAD_LDS16(g, l)                                                     \
    __builtin_amdgcn_global_load_lds(                                         \
        (const __attribute__((address_space(1))) void*)(g),                   \
        (__attribute__((address_space(3))) void*)(l), 16, 0, 0)

// ---------------- kernel 1: exclusive prefix sum of expert sizes ----------
__global__ void offsets_kernel(const int* __restrict__ sizes, int* __restrict__ offs) {
    int e = threadIdx.x;
    int s = 0;
    for (int i = 0; i < e; ++i) s += sizes[i];
    offs[e] = s;
}

// ---------------- kernel 2: W [E][K][N] f32 -> WT [E][N][K] bf16 ----------
__global__ __launch_bounds__(256) void prep_wt(const float* __restrict__ W,
                                               unsigned short* __restrict__ WT) {
    __shared__ float t[32][33];
    int k0 = blockIdx.x * 32, n0 = blockIdx.y * 32, e = blockIdx.z;
    const float* We = W + (size_t)e * IN_SZ * OUT_SZ;
    int tid = threadIdx.x;
    int r = tid >> 3, c4 = (tid & 7) * 4;
    float4 v = *(const float4*)(We + (size_t)(k0 + r) * OUT_SZ + n0 + c4);
    t[r][c4 + 0] = v.x; t[r][c4 + 1] = v.y; t[r][c4 + 2] = v.z; t[r][c4 + 3] = v.w;
    __syncthreads();
    ushort4 o;
    o.x = f2bf(t[c4 + 0][r]);
    o.y = f2bf(t[c4 + 1][r]);
    o.z = f2bf(t[c4 + 2][r]);
    o.w = f2bf(t[c4 + 3][r]);
    unsigned short* O = WT + (size_t)e * IN_SZ * OUT_SZ + (size_t)(n0 + r) * IN_SZ + k0 + c4;
    *(ushort4*)O = o;
}

// ---------------- kernel 3: all-DMA grouped GEMM --------------------------
// A staged as RAW FP32 via global_load_lds (no reg round-trip / ds_write /
// cvt at stage); fp32->bf16 conversion happens at fragment-read time
// (16 v_cvt_pk_bf16_f32 per iter). B staged bf16 as before.
// Asymmetric pipeline: A = 3 bufs staged 2 ahead (HBM-latency exposed,
// ~1.3 iters slack); B = 2 bufs staged 1 ahead (L2-hot). One barrier +
// one counted vmcnt per iter; invariant: end of iter j drains all but
// stageA(j+2) -> vmcnt(4).
// Swizzles (both-sides involution, rule #21):
//   A rows 128 B (8 x 16B slots): slot ^= row&7   (uniform bank spread)
//   B rows  64 B (4 slots):       slot ^= (row>>1)&3  (verified 0-conflict)
__global__ __launch_bounds__(THREADS, 2) void gemm_moe(
    const float* __restrict__ A, const int* __restrict__ sizes,
    const unsigned short* __restrict__ WT, const int* __restrict__ offs,
    float* __restrict__ out)
{
    // bijective XCD swizzle: 3072 blocks, 384 per XCD chunk
    int b0 = blockIdx.x;
    int wg = (b0 & 7) * (E_NUM * RT_MAX * CT_NUM / 8) + (b0 >> 3);
    int ct = wg & (CT_NUM - 1);
    int rt = (wg >> 1) % RT_MAX;
    int e  = wg / (RT_MAX * CT_NUM);

    int size_e = sizes[e];
    int rows0 = rt * BM;
    if (rows0 >= size_e) return;
    int off_e = offs[e];
    int rows_rem = size_e - rows0;                      // >= 1
    int maxr = (rows_rem < BM ? rows_rem : BM) - 1;

    __shared__ float lsA[3][BM * BK];            // 3 x 16 KB (fp32)
    __shared__ unsigned short lsB[2][BN * BK];   // 2 x 16 KB  -> 80 KB total

    int tid = threadIdx.x, l = tid & 63, w = tid >> 6;
    const char* WTe = (const char*)(WT + (size_t)e * IN_SZ * OUT_SZ);
    const char* Abase = (const char*)(A + (size_t)(off_e + rows0) * IN_SZ);

    // ---- A staging: call i stages 8 rows x 128B; lane l -> row (l>>3),
    //      slot l&7; source col chunk = (l&7)^(row&7) (write-linear dest) ----
    const char* gA[4];
    #pragma unroll
    for (int i = 0; i < 4; ++i) {
        int row = (w * 4 + i) * 8 + (l >> 3);        // LDS row 0..127
        int gr = row <= maxr ? row : maxr;           // clamped global row
        gA[i] = Abase + (size_t)gr * (IN_SZ * 4) + (((l & 7) ^ (row & 7)) * 16);
    }
    // ---- B staging (verified): call i stages 16 rows x 64B ----
    const char* gB[4];
    #pragma unroll
    for (int i = 0; i < 4; ++i) {
        int c = w * 4 + i;
        int n = c * 16 + (l >> 2);
        int csrc = ((l & 3) * 16) ^ (((l >> 3) & 3) << 4);
        gB[i] = WTe + (size_t)(ct * BN + n) * (IN_SZ * 2) + csrc;
    }

    auto stageA = [&](int buf, int kt) {
        #pragma unroll
        for (int i = 0; i < 4; ++i)
            GLOAD_LDS16(gA[i] + kt * 128, &lsA[buf][(w * 4 + i) * 256]);
    };
    auto stageB = [&](int buf, int kt) {
        #pragma unroll
        for (int i = 0; i < 4; ++i)
            GLOAD_LDS16(gB[i] + kt * 64, &lsB[buf][(w * 4 + i) * 512]);
    };

    int wm = (w >> 1) * 64, wn = (w & 1) * 128;
    int lrow = l & 15, kq = l >> 4;
    // A fragment addressing: row*128 + ((kq*2+z)^(lrow&7))*16  (row&7==lrow&7)
    int abm[4];
    #pragma unroll
    for (int m = 0; m < 4; ++m) abm[m] = (wm + m * 16 + lrow) * 128;
    int as0 = ((kq * 2 + 0) ^ (lrow & 7)) * 16;
    int as1 = ((kq * 2 + 1) ^ (lrow & 7)) * 16;
    // B fragment addressing (verified)
    int cb = (kq * 16) ^ (((lrow >> 1) & 3) << 4);

    f32x4 acc[4][8] = {};

    #define FRAGS_AND_MFMA(bufA, bufB)                                        \
        {                                                                     \
            const char* pA = (const char*)&lsA[bufA][0];                      \
            const char* pB = (const char*)&lsB[bufB][0];                      \
            f32x4 av[4][2];                                                   \
            _Pragma("unroll")                                                 \
            for (int m = 0; m < 4; ++m) {                                     \
                av[m][0] = *(const f32x4*)(pA + abm[m] + as0);                \
                av[m][1] = *(const f32x4*)(pA + abm[m] + as1);                \
            }                                                                 \
            short8 bfr[8];                                                    \
            _Pragma("unroll")                                                 \
            for (int n = 0; n < 8; ++n)                                       \
                bfr[n] = *(const short8*)(pB + (wn + n * 16 + lrow) * 64 + cb);\
            asm volatile("s_waitcnt lgkmcnt(0)" ::: "memory");                \
            __builtin_amdgcn_sched_barrier(0);                                \
            short8 af[4];                                                     \
            _Pragma("unroll")                                                 \
            for (int m = 0; m < 4; ++m) {                                     \
                u32x4 au;                                                     \
                au[0] = cvtpk(av[m][0][0], av[m][0][1]);                      \
                au[1] = cvtpk(av[m][0][2], av[m][0][3]);                      \
                au[2] = cvtpk(av[m][1][0], av[m][1][1]);                      \
                au[3] = cvtpk(av[m][1][2], av[m][1][3]);                      \
                af[m] = __builtin_bit_cast(short8, au);                       \
            }                                                                 \
            __builtin_amdgcn_s_setprio(1);                                    \
            _Pragma("unroll")                                                 \
            for (int m = 0; m < 4; ++m)                                       \
                _Pragma("unroll")                                             \
                for (int n = 0; n < 8; ++n)                                   \
                    acc[m][n] = __builtin_amdgcn_mfma_f32_16x16x32_bf16(      \
                        af[m], bfr[n], acc[m][n], 0, 0, 0);                   \
            __builtin_amdgcn_s_setprio(0);                                    \
        }

    // ---- prologue: A0,B0,A1 staged; drain A0+B0, keep A1 in flight ----
    stageA(0, 0); stageB(0, 0);
    stageA(1, 1);
    asm volatile("s_waitcnt vmcnt(4)" ::: "memory");
    __builtin_amdgcn_sched_barrier(0);
    __builtin_amdgcn_s_barrier();
    __builtin_amdgcn_sched_barrier(0);

    // ---- main loop (fully unrolled; static buf indices) ----
    // iter j: stageB(j+1) [bufB^ free since barrier j-1]; compute(j);
    //         stageA(j+2) [bufA (j+2)%3 disjoint from j, j+1];
    //         vmcnt(4) drains A(j+1)+B(j+1), keeps A(j+2); barrier.
    #pragma unroll
    for (int j = 0; j < JT; ++j) {
        if (j + 1 < JT) stageB((j + 1) & 1, j + 1);
        FRAGS_AND_MFMA(j % 3, j & 1);
        if (j + 2 < JT) stageA((j + 2) % 3, j + 2);
        if (j < JT - 1) {
            if (j + 2 < JT) {
                asm volatile("s_waitcnt vmcnt(4)" ::: "memory");
            } else {
                asm volatile("s_waitcnt vmcnt(0)" ::: "memory");
            }
            __builtin_amdgcn_sched_barrier(0);
            __builtin_amdgcn_s_barrier();
            __builtin_amdgcn_sched_barrier(0);
        }
    }

    // epilogue: C/D layout col = lane&15, row = (lane>>4)*4 + reg
    float* outb = out + (size_t)(off_e + rows0) * OUT_SZ + ct * BN + wn;
    #pragma unroll
    for (int m = 0; m < 4; ++m) {
        #pragma unroll
        for (int j = 0; j < 4; ++j) {
            int rl = wm + m * 16 + kq * 4 + j;
            if (rl < rows_rem) {
                float* po = outb + (size_t)rl * OUT_SZ + lrow;
                #pragma unroll
                for (int n = 0; n < 8; ++n)
                    po[n * 16] = acc[m][n][j];
            }
        }
    }
}

extern "C" void kernel_launch(void* const* d_in, const int* in_sizes, int n_in,
                              void* d_out, int out_size, void* d_ws, size_t ws_size,
                              hipStream_t stream) {
    const float* A      = (const float*)d_in[0];
    const int* sizes    = (const int*)d_in[1];
    const float* W      = (const float*)d_in[2];
    float* out          = (float*)d_out;

    unsigned short* WT  = (unsigned short*)d_ws;                       // 32 MB
    int* offs           = (int*)((char*)d_ws + (size_t)E_NUM * IN_SZ * OUT_SZ * 2);

    offsets_kernel<<<1, E_NUM, 0, stream>>>(sizes, offs);
    prep_wt<<<dim3(IN_SZ / 32, OUT_SZ / 32, E_NUM), 256, 0, stream>>>(W, WT);
    gemm_moe<<<E_NUM * RT_MAX * CT_NUM, THREADS, 0, stream>>>(A, sizes, WT, offs, out);
}